// Round 9
// baseline (57.823 us; speedup 1.0000x reference)
//
#include <hip/hip_runtime.h>
#include <hip/hip_bf16.h>

#define NB 64
#define LQ 32
#define LD 256
#define DD 128
#define NWAY 8
#define NBLK (NB * NWAY * 4)   // 2048 blocks: one per (b, n, quarter)

typedef __attribute__((ext_vector_type(8))) short short8;
typedef __attribute__((ext_vector_type(4))) float f32x4;

static __device__ __forceinline__ unsigned short f2bf(float f) {
    unsigned int u = __float_as_uint(f);
    u += 0x7fffu + ((u >> 16) & 1u);   // round-to-nearest-even
    return (unsigned short)(u >> 16);
}
static __device__ __forceinline__ unsigned int pk2(float a, float b) {
    return (unsigned int)f2bf(a) | ((unsigned int)f2bf(b) << 16);
}

union bfr { unsigned u[4]; short8 v; };

// Block bid: b = bid&63, r = bid>>6, n = r&7, qt = r>>3. Same-b blocks all
// have bid ≡ b (mod 8) -> same XCD -> Q re-reads are XCD-L2 hits (inputs are
// L2/L3-warm during timed replays anyway). 256 threads = 4 waves; wave w owns
// doc rows qt*64 + w*16 + (lane&15). ZERO LDS staging / zero barriers in the
// dot loop: B-fragments loaded global->regs (lane l&15 = doc row = its own
// MFMA output column -> mask, 1/||d||, and max-gating all lane-local).
// Doc rows unnormalized bf16; 1/||d|| post-MFMA (max commutes with positive
// scale). Masked rows never loaded (zeros), gated from the max.
// <=64 VGPR (R4 compiled to 64 with MORE live state) -> 8 blocks/CU = 32 waves/CU.
__global__ __launch_bounds__(256, 8) void colbert_part_kernel(
    const float* __restrict__ qreps,   // [B][LQ][DD]
    const float* __restrict__ dreps,   // [B][NWAY][LD][DD]
    const int*   __restrict__ masks,   // [B][NWAY][LD]
    float*       __restrict__ qpart)   // [512*4][LQ] per-q partial max
{
    const int bid  = blockIdx.x;
    const int b    = bid & 63;
    const int r_   = bid >> 6;
    const int n    = r_ & 7;
    const int qt   = r_ >> 3;
    const int bn   = b * NWAY + n;
    const int tid  = threadIdx.x;
    const int lane = tid & 63;
    const int w    = tid >> 6;         // 0..3
    const int fr   = lane & 15;        // fragment row/col index
    const int fp   = lane >> 4;        // k-pack 0..3

    __shared__ float qmaxw[4][LQ];

    const int myrow = qt * 64 + w * 16 + fr;     // my doc row (= my output col)

    // ---- mask for my row (gates doc load AND max) ----
    const int rm = masks[(size_t)bn * LD + myrow];

    // ---- Q -> normalized bf16 A-fragments in registers (L2/L3-served) ----
    bfr afrag[2][4];
    #pragma unroll
    for (int qh = 0; qh < 2; ++qh) {
        const float* qsrc = qreps + ((size_t)b * LQ + qh * 16 + fr) * DD + fp * 8;
        float qv[32];
        float ss = 0.f;
        #pragma unroll
        for (int kc = 0; kc < 4; ++kc) {
            float4 f0 = reinterpret_cast<const float4*>(qsrc + kc * 32)[0];
            float4 f1 = reinterpret_cast<const float4*>(qsrc + kc * 32)[1];
            qv[kc*8+0]=f0.x; qv[kc*8+1]=f0.y; qv[kc*8+2]=f0.z; qv[kc*8+3]=f0.w;
            qv[kc*8+4]=f1.x; qv[kc*8+5]=f1.y; qv[kc*8+6]=f1.z; qv[kc*8+7]=f1.w;
            ss += f0.x*f0.x+f0.y*f0.y+f0.z*f0.z+f0.w*f0.w
                + f1.x*f1.x+f1.y*f1.y+f1.z*f1.z+f1.w*f1.w;
        }
        ss += __shfl_xor(ss, 16);      // lanes sharing q row fr: l, l^16, l^32
        ss += __shfl_xor(ss, 32);
        const float rn = rsqrtf(fmaxf(ss, 1e-24f));
        #pragma unroll
        for (int kc = 0; kc < 4; ++kc) {
            afrag[qh][kc].u[0] = pk2(qv[kc*8+0]*rn, qv[kc*8+1]*rn);
            afrag[qh][kc].u[1] = pk2(qv[kc*8+2]*rn, qv[kc*8+3]*rn);
            afrag[qh][kc].u[2] = pk2(qv[kc*8+4]*rn, qv[kc*8+5]*rn);
            afrag[qh][kc].u[3] = pk2(qv[kc*8+6]*rn, qv[kc*8+7]*rn);
        }
    }

    // ---- my doc row: gated global -> packed bf16 regs + 1/||d|| ----
    unsigned dp[16];
    float ss = 0.f;
    if (rm) {
        const float* src = dreps + ((size_t)bn * LD + myrow) * DD + fp * 8;
        #pragma unroll
        for (int kc = 0; kc < 4; ++kc) {
            float4 f0 = reinterpret_cast<const float4*>(src + kc * 32)[0];
            float4 f1 = reinterpret_cast<const float4*>(src + kc * 32)[1];
            ss += f0.x*f0.x+f0.y*f0.y+f0.z*f0.z+f0.w*f0.w
                + f1.x*f1.x+f1.y*f1.y+f1.z*f1.z+f1.w*f1.w;
            dp[kc*4+0] = pk2(f0.x, f0.y);
            dp[kc*4+1] = pk2(f0.z, f0.w);
            dp[kc*4+2] = pk2(f1.x, f1.y);
            dp[kc*4+3] = pk2(f1.z, f1.w);
        }
    } else {
        #pragma unroll
        for (int i = 0; i < 16; ++i) dp[i] = 0u;
    }
    // the 4 lanes of a row share rm -> convergent reduce
    ss += __shfl_xor(ss, 16);
    ss += __shfl_xor(ss, 32);
    const float rnd = rsqrtf(fmaxf(ss, 1e-24f));

    // ---- MFMA: 2 q-halves x K=128 ----
    f32x4 acc0 = {0.f, 0.f, 0.f, 0.f};
    f32x4 acc1 = {0.f, 0.f, 0.f, 0.f};
    #pragma unroll
    for (int kc = 0; kc < 4; ++kc) {
        bfr bb;
        bb.u[0] = dp[kc*4+0]; bb.u[1] = dp[kc*4+1];
        bb.u[2] = dp[kc*4+2]; bb.u[3] = dp[kc*4+3];
        acc0 = __builtin_amdgcn_mfma_f32_16x16x32_bf16(afrag[0][kc].v, bb.v, acc0, 0, 0, 0);
        acc1 = __builtin_amdgcn_mfma_f32_16x16x32_bf16(afrag[1][kc].v, bb.v, acc1, 0, 0, 0);
    }

    float rmax[2][4];
    #pragma unroll
    for (int r = 0; r < 4; ++r) {
        rmax[0][r] = rm ? acc0[r] * rnd : -1e30f;
        rmax[1][r] = rm ? acc1[r] * rnd : -1e30f;
    }

    // ---- reduce max over the wave's 16 doc columns (within fp group) ----
    #pragma unroll
    for (int qh = 0; qh < 2; ++qh)
        #pragma unroll
        for (int r = 0; r < 4; ++r) {
            float m = rmax[qh][r];
            m = fmaxf(m, __shfl_xor(m, 1));
            m = fmaxf(m, __shfl_xor(m, 2));
            m = fmaxf(m, __shfl_xor(m, 4));
            m = fmaxf(m, __shfl_xor(m, 8));
            rmax[qh][r] = m;
        }
    if (fr == 0) {
        #pragma unroll
        for (int qh = 0; qh < 2; ++qh)
            #pragma unroll
            for (int r = 0; r < 4; ++r)
                qmaxw[w][qh * 16 + fp * 4 + r] = rmax[qh][r];
    }
    __syncthreads();

    // ---- combine 4 waves (4 doc groups of 16) -> per-q partial max -> ws ----
    if (w == 0 && lane < 32) {
        const float s = fmaxf(fmaxf(qmaxw[0][lane], qmaxw[1][lane]),
                              fmaxf(qmaxw[2][lane], qmaxw[3][lane]));
        qpart[((size_t)bn * 4 + qt) * LQ + lane] = s;
    }
}

// One block, 512 threads: thread bn combines 4 quarters, then softmax + KL.
__global__ __launch_bounds__(512) void colbert_loss_kernel(
    const float* __restrict__ qpart,    // [512*4][LQ]
    const float* __restrict__ labels,   // [B][2*NWAY]
    float*       __restrict__ out)
{
    const int bn = threadIdx.x;         // 0..511
    const int b  = bn >> 3;
    const int n  = bn & 7;

    float vmax[LQ];
    const float* src = qpart + (size_t)bn * 4 * LQ;
    #pragma unroll
    for (int i = 0; i < 8; ++i) {
        float4 f = reinterpret_cast<const float4*>(src)[i];
        vmax[4*i] = f.x; vmax[4*i+1] = f.y; vmax[4*i+2] = f.z; vmax[4*i+3] = f.w;
    }
    #pragma unroll
    for (int h = 1; h < 4; ++h) {
        #pragma unroll
        for (int i = 0; i < 8; ++i) {
            float4 f = reinterpret_cast<const float4*>(src + h * LQ)[i];
            vmax[4*i]   = fmaxf(vmax[4*i],   f.x);
            vmax[4*i+1] = fmaxf(vmax[4*i+1], f.y);
            vmax[4*i+2] = fmaxf(vmax[4*i+2], f.z);
            vmax[4*i+3] = fmaxf(vmax[4*i+3], f.w);
        }
    }
    float score = 0.f;
    #pragma unroll
    for (int q = 0; q < LQ; ++q) score += vmax[q];

    // softmax over the 8 n's (consecutive lanes within the wave)
    float m = score;
    m = fmaxf(m, __shfl_xor(m, 1)); m = fmaxf(m, __shfl_xor(m, 2)); m = fmaxf(m, __shfl_xor(m, 4));
    float e = expf(score - m);
    float se = e;
    se += __shfl_xor(se, 1); se += __shfl_xor(se, 2); se += __shfl_xor(se, 4);
    const float lse = m + logf(se);
    const float ls  = score - lse;

    const float tg = labels[b * 2 * NWAY + n];
    const float wv = labels[b * 2 * NWAY + NWAY + n];
    float aterm = expf(tg) * (tg - ls);
    float pterm = ls * wv;

    #pragma unroll
    for (int d = 1; d < 64; d <<= 1) {
        aterm += __shfl_xor(aterm, d);
        pterm += __shfl_xor(pterm, d);
    }
    __shared__ float wa[8], wp[8];
    const int wv_id = threadIdx.x >> 6;
    if ((threadIdx.x & 63) == 0) { wa[wv_id] = aterm; wp[wv_id] = pterm; }
    __syncthreads();
    if (threadIdx.x == 0) {
        float A = 0.f, P = 0.f;
        #pragma unroll
        for (int i = 0; i < 8; ++i) { A += wa[i]; P += wp[i]; }
        out[0] = A / 512.0f - 0.1f * P;
    }
}

extern "C" void kernel_launch(void* const* d_in, const int* in_sizes, int n_in,
                              void* d_out, int out_size, void* d_ws, size_t ws_size,
                              hipStream_t stream) {
    const float* qreps  = (const float*)d_in[0];
    const float* dreps  = (const float*)d_in[1];
    const int*   masks  = (const int*)d_in[2];
    const float* labels = (const float*)d_in[3];
    float* qpart = (float*)d_ws;             // 2048*32 floats = 256 KB
    float* out   = (float*)d_out;

    colbert_part_kernel<<<NBLK, 256, 0, stream>>>(qreps, dreps, masks, qpart);
    colbert_loss_kernel<<<1, 512, 0, stream>>>(qpart, labels, out);
}

// Round 10
// 17.478 us; speedup vs baseline: 3.3084x; 3.3084x over previous
//
#include <hip/hip_runtime.h>
#include <hip/hip_bf16.h>

#define NB 64
#define LQ 32
#define LD 256
#define DD 128
#define NWAY 8
#define NBLOCKS (NB * NWAY)   // 512
#define DSROW 136             // shorts per row: 128 data + 8 pad (272B stride)
// dynamic LDS: ds[256][136] + qs[32][136] + rnds[256] + qmaxs[8][32]
#define SMEM_BYTES ((256 + 32) * DSROW * 2 + 256 * 4 + 256 * 4)   // 80384 B

typedef __attribute__((ext_vector_type(8))) short short8;
typedef __attribute__((ext_vector_type(4))) float f32x4;

static __device__ __forceinline__ unsigned short f2bf(float f) {
    unsigned int u = __float_as_uint(f);
    u += 0x7fffu + ((u >> 16) & 1u);   // round-to-nearest-even
    return (unsigned short)(u >> 16);
}
static __device__ __forceinline__ unsigned int pk2(float a, float b) {
    return (unsigned int)f2bf(a) | ((unsigned int)f2bf(b) << 16);
}

// One block per (b,n): b=bid&63, n=bid>>6 (same-b blocks -> same XCD L2).
// 1024 threads = 16 waves; LDS 80384B -> exactly 2 blocks/CU = 32 waves/CU
// (VGPR permitting; bounds cap 128 so NO spill possible - R8 lesson).
// Single-phase: all gated global loads -> pack bf16 -> LDS -> ONE barrier ->
// MFMA phase (wave = (kq 0..7, qh 0..1), 32 doc cols per wave).
// Doc rows unnormalized bf16; 1/||d|| post-MFMA (max commutes with positive
// scales). Masked rows never loaded; garbage only reaches gated-out columns.
__global__ __launch_bounds__(1024, 4) void colbert_scores_kernel(
    const float* __restrict__ qreps,   // [B][LQ][DD]
    const float* __restrict__ dreps,   // [B][NWAY][LD][DD]
    const int*   __restrict__ masks,   // [B][NWAY][LD]
    float*       __restrict__ scores)  // [512]
{
    extern __shared__ unsigned short smem[];
    unsigned short* ds_   = smem;                                 // [256][DSROW]
    unsigned short* qs    = smem + 256 * DSROW;                   // [32][DSROW]
    float*          rnds  = (float*)(smem + (256 + 32) * DSROW);  // [256]
    float*          qmaxs = rnds + 256;                           // [8][32]

    const int bid  = blockIdx.x;
    const int b    = bid & 63;
    const int n    = bid >> 6;
    const int bn   = b * NWAY + n;
    const int tid  = threadIdx.x;
    const int lane = tid & 63;
    const int w    = tid >> 6;         // 0..15
    const int fr   = lane & 15;
    const int fp   = lane >> 4;
    const int qh   = w & 1;
    const int kq   = w >> 1;           // 0..7

    const int drow = tid >> 2;         // doc row 0..255
    const int dseg = tid & 3;          // 32-float segment of the row

    // ---- register masks: row gate + this wave's 32 output columns ----
    const int rm = masks[(size_t)bn * LD + drow];
    int cm[2];
    cm[0] = masks[(size_t)bn * LD + kq * 32 + fr];
    cm[1] = masks[(size_t)bn * LD + kq * 32 + 16 + fr];

    // ---- issue gated doc loads: 8x float4 (quarter row) ----
    float4 fa[8];
    const float* dsrc = dreps + ((size_t)bn * LD + drow) * DD + dseg * 32;
    if (rm) {
        #pragma unroll
        for (int i = 0; i < 8; ++i) fa[i] = reinterpret_cast<const float4*>(dsrc)[i];
    }

    // ---- Q: 32 threads/row, one float4 each; normalize; pack -> LDS ----
    {
        const int qrow = tid >> 5;     // 0..31
        const int qseg = tid & 31;     // 4 floats each
        const float* qsrc = qreps + ((size_t)b * LQ + qrow) * DD + qseg * 4;
        float4 qf = *reinterpret_cast<const float4*>(qsrc);
        float qss = qf.x*qf.x + qf.y*qf.y + qf.z*qf.z + qf.w*qf.w;
        qss += __shfl_xor(qss, 1);  qss += __shfl_xor(qss, 2);
        qss += __shfl_xor(qss, 4);  qss += __shfl_xor(qss, 8);
        qss += __shfl_xor(qss, 16);
        const float qrn = rsqrtf(fmaxf(qss, 1e-24f));
        unsigned q2[2] = { pk2(qf.x*qrn, qf.y*qrn), pk2(qf.z*qrn, qf.w*qrn) };
        unsigned short* qdst = &qs[qrow * DSROW + qseg * 4];
        *reinterpret_cast<uint2*>(qdst) = *reinterpret_cast<const uint2*>(q2);
    }

    // ---- doc: ssq + pack raw bf16 -> LDS; rnds = 1/||row|| ----
    if (rm) {   // rm uniform across the row's 4 lanes -> convergent shfl
        float ss = 0.f;
        #pragma unroll
        for (int i = 0; i < 8; ++i)
            ss += fa[i].x*fa[i].x + fa[i].y*fa[i].y + fa[i].z*fa[i].z + fa[i].w*fa[i].w;
        ss += __shfl_xor(ss, 1);
        ss += __shfl_xor(ss, 2);
        if (dseg == 0) rnds[drow] = rsqrtf(fmaxf(ss, 1e-24f));

        unsigned short* dst = &ds_[drow * DSROW + dseg * 32];
        #pragma unroll
        for (int i = 0; i < 4; ++i) {
            unsigned dpk[4] = {
                pk2(fa[2*i].x,   fa[2*i].y),   pk2(fa[2*i].z,   fa[2*i].w),
                pk2(fa[2*i+1].x, fa[2*i+1].y), pk2(fa[2*i+1].z, fa[2*i+1].w) };
            reinterpret_cast<uint4*>(dst)[i] = *reinterpret_cast<const uint4*>(dpk);
        }
    }

    __syncthreads();   // THE barrier: qs, ds_, rnds visible

    // ---- A-fragments from LDS (read once) ----
    short8 afr[4];
    const unsigned short* ap = &qs[(qh * 16 + fr) * DSROW + fp * 8];
    #pragma unroll
    for (int kc = 0; kc < 4; ++kc)
        afr[kc] = *reinterpret_cast<const short8*>(ap + kc * 32);

    // ---- MFMA: this wave covers doc cols kq*32 .. kq*32+31 ----
    float rmax[4] = {-1e30f, -1e30f, -1e30f, -1e30f};
    #pragma unroll
    for (int c = 0; c < 2; ++c) {
        const int dcol = kq * 32 + c * 16 + fr;
        const unsigned short* bp = &ds_[dcol * DSROW + fp * 8];
        f32x4 acc = {0.f, 0.f, 0.f, 0.f};
        #pragma unroll
        for (int kc = 0; kc < 4; ++kc) {
            short8 bb = *reinterpret_cast<const short8*>(bp + kc * 32);
            acc = __builtin_amdgcn_mfma_f32_16x16x32_bf16(afr[kc], bb, acc, 0, 0, 0);
        }
        if (cm[c]) {
            const float rnd = rnds[dcol];
            #pragma unroll
            for (int r = 0; r < 4; ++r) rmax[r] = fmaxf(rmax[r], acc[r] * rnd);
        }
    }

    // ---- reduce max over 16 doc-columns within each 16-lane group ----
    #pragma unroll
    for (int r = 0; r < 4; ++r) {
        float m = rmax[r];
        m = fmaxf(m, __shfl_xor(m, 1));
        m = fmaxf(m, __shfl_xor(m, 2));
        m = fmaxf(m, __shfl_xor(m, 4));
        m = fmaxf(m, __shfl_xor(m, 8));
        rmax[r] = m;
    }
    if (fr == 0) {
        #pragma unroll
        for (int r = 0; r < 4; ++r)
            qmaxs[kq * 32 + qh * 16 + fp * 4 + r] = rmax[r];
    }
    __syncthreads();

    // ---- combine the 8 kq groups, sum over q rows, store score ----
    if (w == 0) {
        float s = 0.f;
        if (lane < 32) {
            s = qmaxs[lane];
            #pragma unroll
            for (int k = 1; k < 8; ++k) s = fmaxf(s, qmaxs[k * 32 + lane]);
        }
        s += __shfl_xor(s, 1);  s += __shfl_xor(s, 2);  s += __shfl_xor(s, 4);
        s += __shfl_xor(s, 8);  s += __shfl_xor(s, 16); s += __shfl_xor(s, 32);
        if (lane == 0) scores[bn] = s;
    }
}

// One wave: thread b handles batch row b.
__global__ __launch_bounds__(64) void colbert_loss_kernel(
    const float* __restrict__ scores,   // [512]
    const float* __restrict__ labels,   // [B][2*NWAY]
    float*       __restrict__ out)
{
    const int b = threadIdx.x;
    float sc[NWAY];
    float m = -1e30f;
    #pragma unroll
    for (int j = 0; j < NWAY; ++j) { sc[j] = scores[b * NWAY + j]; m = fmaxf(m, sc[j]); }
    float se = 0.f;
    #pragma unroll
    for (int j = 0; j < NWAY; ++j) se += expf(sc[j] - m);
    const float lse = m + logf(se);

    float lossb = 0.f, posb = 0.f;
    #pragma unroll
    for (int j = 0; j < NWAY; ++j) {
        const float ls = sc[j] - lse;
        const float tg = labels[b * 2 * NWAY + j];
        const float wv = labels[b * 2 * NWAY + NWAY + j];
        lossb += expf(tg) * (tg - ls);
        posb  += ls * wv;
    }
    float a = lossb, p = posb;
    #pragma unroll
    for (int d = 1; d < 64; d <<= 1) { a += __shfl_xor(a, d); p += __shfl_xor(p, d); }
    if (b == 0) out[0] = a / 512.0f - 0.1f * p;
}

extern "C" void kernel_launch(void* const* d_in, const int* in_sizes, int n_in,
                              void* d_out, int out_size, void* d_ws, size_t ws_size,
                              hipStream_t stream) {
    const float* qreps  = (const float*)d_in[0];
    const float* dreps  = (const float*)d_in[1];
    const int*   masks  = (const int*)d_in[2];
    const float* labels = (const float*)d_in[3];
    float* scoresp = (float*)d_ws;           // 512 floats
    float* out     = (float*)d_out;

    // allow >64KB dynamic LDS (idempotent, capture-safe)
    hipFuncSetAttribute((const void*)colbert_scores_kernel,
                        hipFuncAttributeMaxDynamicSharedMemorySize, SMEM_BYTES);

    colbert_scores_kernel<<<NBLOCKS, 1024, SMEM_BYTES, stream>>>(qreps, dreps, masks, scoresp);
    colbert_loss_kernel<<<1, 64, 0, stream>>>(scoresp, labels, out);
}

// Round 11
// 14.783 us; speedup vs baseline: 3.9116x; 1.1823x over previous
//
#include <hip/hip_runtime.h>
#include <hip/hip_bf16.h>

#define NB 64
#define LQ 32
#define LD 256
#define DD 128
#define NWAY 8
#define KT 64            // doc rows per tile; 4 tiles
#define NBLOCKS (NB * NWAY)   // 512
#define LDSROW 136       // 128 + 8 bf16 pad -> 272B row stride, 16B aligned

typedef __attribute__((ext_vector_type(8))) short short8;
typedef __attribute__((ext_vector_type(4))) float f32x4;

static __device__ __forceinline__ unsigned short f2bf(float f) {
    unsigned int u = __float_as_uint(f);
    u += 0x7fffu + ((u >> 16) & 1u);   // round-to-nearest-even
    return (unsigned short)(u >> 16);
}
static __device__ __forceinline__ unsigned int pk2(float a, float b) {
    return (unsigned int)f2bf(a) | ((unsigned int)f2bf(b) << 16);
}

// One block per (b,n), 512 threads = 8 waves (wave = kq*2+qh).
// b=bid&63, n=bid>>6: the 8 blocks sharing b land on one XCD -> Q L2-hits.
// R4-pipeline refined: ALL masks in registers at cycle 0 (no LDS mask, no
// barrier dependency for gating), all 512 threads share Q normalize
// (16 thr/row), A-fragments hoisted to registers once after barrier #1.
// Doc rows unnormalized bf16; 1/||d|| post-MFMA (max commutes with positive
// scales). Masked rows never loaded.
__global__ __launch_bounds__(512, 4) void colbert_scores_kernel(
    const float* __restrict__ qreps,   // [B][LQ][DD]
    const float* __restrict__ dreps,   // [B][NWAY][LD][DD]
    const int*   __restrict__ masks,   // [B][NWAY][LD]
    float*       __restrict__ scores)  // [512]
{
    const int bid  = blockIdx.x;
    const int b    = bid & 63;
    const int n    = bid >> 6;
    const int bn   = b * NWAY + n;
    const int tid  = threadIdx.x;
    const int lane = tid & 63;
    const int w    = tid >> 6;

    __shared__ __align__(16) unsigned short qs[LQ * LDSROW];       // normalized q bf16
    __shared__ __align__(16) unsigned short dsb[2][KT * LDSROW];   // raw doc bf16, dbuf
    __shared__ float rnds[2][KT];
    __shared__ float qmaxs[4][LQ];

    const int row = tid >> 3;          // doc staging row (0..63)
    const int seg = tid & 7;           // 16-float segment
    const int fr  = lane & 15;
    const int fp  = lane >> 4;
    const int qh  = w & 1;
    const int kq  = w >> 1;            // 0..3

    // ---- cycle 0: ALL masks -> registers (row gates + my mfma column gates) ----
    int mymask[4], cmask[4];
    #pragma unroll
    for (int t = 0; t < 4; ++t) {
        mymask[t] = masks[(size_t)bn * LD + t * KT + row];
        cmask[t]  = masks[(size_t)bn * LD + t * KT + kq * 16 + fr];
    }

    // ---- Q: 16 threads/row (8 floats each), issue loads early ----
    {
        const int qrow = tid >> 4;     // 0..31
        const int qseg = tid & 15;     // 8-float segment
        const float* qsrc = qreps + ((size_t)b * LQ + qrow) * DD + qseg * 8;
        float4 qa = reinterpret_cast<const float4*>(qsrc)[0];
        float4 qb = reinterpret_cast<const float4*>(qsrc)[1];
        float ss = qa.x*qa.x + qa.y*qa.y + qa.z*qa.z + qa.w*qa.w
                 + qb.x*qb.x + qb.y*qb.y + qb.z*qb.z + qb.w*qb.w;
        ss += __shfl_xor(ss, 1); ss += __shfl_xor(ss, 2);
        ss += __shfl_xor(ss, 4); ss += __shfl_xor(ss, 8);
        const float rn = rsqrtf(fmaxf(ss, 1e-24f));
        unsigned int qp[4] = { pk2(qa.x*rn, qa.y*rn), pk2(qa.z*rn, qa.w*rn),
                               pk2(qb.x*rn, qb.y*rn), pk2(qb.z*rn, qb.w*rn) };
        unsigned short* dst = &qs[qrow * LDSROW + qseg * 8];
        *reinterpret_cast<uint4*>(dst) = *reinterpret_cast<const uint4*>(qp);
    }

    float va[16], vb[16];

    // gated on REGISTER mask -> doc loads issue with no barrier dependency
    auto prefetch = [&](float (&v)[16], int t) {
        if (mymask[t]) {
            const float* src = dreps + ((size_t)bn * LD + t * KT + row) * DD + seg * 16;
            #pragma unroll
            for (int i = 0; i < 4; ++i) {
                float4 f = reinterpret_cast<const float4*>(src)[i];
                v[4*i] = f.x; v[4*i+1] = f.y; v[4*i+2] = f.z; v[4*i+3] = f.w;
            }
        }
    };
    // pack-only staging; mymask uniform across the row's 8 lanes -> shfl safe
    auto stagewrite = [&](float (&v)[16], int t, int bf) {
        if (mymask[t]) {
            unsigned int dp[8];
            #pragma unroll
            for (int i = 0; i < 8; ++i) dp[i] = pk2(v[2*i], v[2*i+1]);
            unsigned short* dst = &dsb[bf][row * LDSROW + seg * 16];
            reinterpret_cast<uint4*>(dst)[0] = *reinterpret_cast<const uint4*>(&dp[0]);
            reinterpret_cast<uint4*>(dst)[1] = *reinterpret_cast<const uint4*>(&dp[4]);
            float ss = 0.f;
            #pragma unroll
            for (int i = 0; i < 16; ++i) ss += v[i] * v[i];
            ss += __shfl_xor(ss, 1); ss += __shfl_xor(ss, 2); ss += __shfl_xor(ss, 4);
            if (seg == 0) rnds[bf][row] = rsqrtf(fmaxf(ss, 1e-24f));
        }
    };

    float rmax[4] = {-1e30f, -1e30f, -1e30f, -1e30f};
    short8 afr[4];

    auto mfma_max = [&](int t, int bf) {
        const int drow = kq * 16 + fr;     // doc row within tile -> output column
        const unsigned short* bptr = &dsb[bf][drow * LDSROW + fp * 8];
        f32x4 acc = {0.f, 0.f, 0.f, 0.f};
        #pragma unroll
        for (int kc = 0; kc < 4; ++kc) {
            short8 bb = *reinterpret_cast<const short8*>(bptr + kc * 32);
            acc = __builtin_amdgcn_mfma_f32_16x16x32_bf16(afr[kc], bb, acc, 0, 0, 0);
        }
        if (cmask[t]) {
            const float rnd = rnds[bf][drow];
            #pragma unroll
            for (int r = 0; r < 4; ++r) rmax[r] = fmaxf(rmax[r], acc[r] * rnd);
        }
    };

    // ---- 4-tile pipeline, 2 LDS buffers, distance-2 register prefetch ----
    prefetch(va, 0);  prefetch(vb, 1);
    stagewrite(va, 0, 0);
    __syncthreads();               // dsb[0] (t0) + qs ready

    // hoist A-fragments once (register reuse across all 4 tiles)
    {
        const unsigned short* ap = &qs[(qh * 16 + fr) * LDSROW + fp * 8];
        #pragma unroll
        for (int kc = 0; kc < 4; ++kc)
            afr[kc] = *reinterpret_cast<const short8*>(ap + kc * 32);
    }

    prefetch(va, 2);
    mfma_max(0, 0);                // read dsb[0]
    stagewrite(vb, 1, 1);          // write dsb[1]
    __syncthreads();               // dsb[1] (t1) ready, dsb[0] free
    prefetch(vb, 3);
    mfma_max(1, 1);
    stagewrite(va, 2, 0);
    __syncthreads();
    mfma_max(2, 0);
    stagewrite(vb, 3, 1);
    __syncthreads();
    mfma_max(3, 1);

    // ---- reduce max over 16 doc-columns within wave ----
    #pragma unroll
    for (int r = 0; r < 4; ++r) {
        float m = rmax[r];
        m = fmaxf(m, __shfl_xor(m, 1));
        m = fmaxf(m, __shfl_xor(m, 2));
        m = fmaxf(m, __shfl_xor(m, 4));
        m = fmaxf(m, __shfl_xor(m, 8));
        rmax[r] = m;
    }
    if (fr == 0) {
        const int qr = qh * 16 + fp * 4;
        #pragma unroll
        for (int r = 0; r < 4; ++r) qmaxs[kq][qr + r] = rmax[r];
    }
    __syncthreads();

    // ---- combine k-quarters, sum over q rows, store score ----
    if (w == 0) {
        float s = 0.f;
        if (lane < 32)
            s = fmaxf(fmaxf(qmaxs[0][lane], qmaxs[1][lane]),
                      fmaxf(qmaxs[2][lane], qmaxs[3][lane]));
        s += __shfl_xor(s, 1);  s += __shfl_xor(s, 2);  s += __shfl_xor(s, 4);
        s += __shfl_xor(s, 8);  s += __shfl_xor(s, 16); s += __shfl_xor(s, 32);
        if (lane == 0) scores[bn] = s;
    }
}

// One wave: thread b handles batch row b.
__global__ __launch_bounds__(64) void colbert_loss_kernel(
    const float* __restrict__ scores,   // [512]
    const float* __restrict__ labels,   // [B][2*NWAY]
    float*       __restrict__ out)
{
    const int b = threadIdx.x;
    float sc[NWAY];
    float m = -1e30f;
    #pragma unroll
    for (int j = 0; j < NWAY; ++j) { sc[j] = scores[b * NWAY + j]; m = fmaxf(m, sc[j]); }
    float se = 0.f;
    #pragma unroll
    for (int j = 0; j < NWAY; ++j) se += expf(sc[j] - m);
    const float lse = m + logf(se);

    float lossb = 0.f, posb = 0.f;
    #pragma unroll
    for (int j = 0; j < NWAY; ++j) {
        const float ls = sc[j] - lse;
        const float tg = labels[b * 2 * NWAY + j];
        const float wv = labels[b * 2 * NWAY + NWAY + j];
        lossb += expf(tg) * (tg - ls);
        posb  += ls * wv;
    }
    float a = lossb, p = posb;
    #pragma unroll
    for (int d = 1; d < 64; d <<= 1) { a += __shfl_xor(a, d); p += __shfl_xor(p, d); }
    if (b == 0) out[0] = a / 512.0f - 0.1f * p;
}

extern "C" void kernel_launch(void* const* d_in, const int* in_sizes, int n_in,
                              void* d_out, int out_size, void* d_ws, size_t ws_size,
                              hipStream_t stream) {
    const float* qreps  = (const float*)d_in[0];
    const float* dreps  = (const float*)d_in[1];
    const int*   masks  = (const int*)d_in[2];
    const float* labels = (const float*)d_in[3];
    float* scoresp = (float*)d_ws;           // 512 floats
    float* out     = (float*)d_out;

    colbert_scores_kernel<<<NBLOCKS, 512, 0, stream>>>(qreps, dreps, masks, scoresp);
    colbert_loss_kernel<<<1, 64, 0, stream>>>(scoresp, labels, out);
}